// Round 8
// baseline (466.014 us; speedup 1.0000x reference)
//
#include <hip/hip_runtime.h>
#include <cmath>
#include <cstdint>
#include <cstddef>

typedef __bf16 bf16_t;
typedef __bf16 bf16x8 __attribute__((ext_vector_type(8)));
typedef float  f32x4  __attribute__((ext_vector_type(4)));

#define B_   2
#define T_   2048
#define E_   1024
#define H_   16
#define D_   64
#define FF_  4096
#define NROW (B_ * T_)   // 4096
#define QS_  (3 * E_)    // packed QKV row stride
#define NTI  (T_ / 64)   // 32 q-tiles

// workgroup barrier WITHOUT vmcnt drain: LDS visibility needs lgkmcnt(0)
// only; register-destined global loads stay in flight across the barrier.
__device__ __forceinline__ void wg_barrier() {
    asm volatile("s_waitcnt lgkmcnt(0)\n\ts_barrier" ::: "memory");
}

// ---------------------------------------------------------------- LN ----
__global__ __launch_bounds__(256) void ln_kernel(
    const float* __restrict__ x, const float* __restrict__ g,
    const float* __restrict__ bta, bf16_t* __restrict__ out)
{
    int row = blockIdx.x;
    int tid = threadIdx.x;
    const float4* xr = (const float4*)(x + (size_t)row * E_);
    float4 v = xr[tid];
    float s  = v.x + v.y + v.z + v.w;
    float ss = v.x * v.x + v.y * v.y + v.z * v.z + v.w * v.w;
#pragma unroll
    for (int off = 32; off; off >>= 1) {
        s  += __shfl_xor(s, off);
        ss += __shfl_xor(ss, off);
    }
    __shared__ float red[8];
    int wave = tid >> 6, lane = tid & 63;
    if (lane == 0) { red[wave] = s; red[4 + wave] = ss; }
    __syncthreads();
    s  = red[0] + red[1] + red[2] + red[3];
    ss = red[4] + red[5] + red[6] + red[7];
    float mu   = s * (1.0f / E_);
    float var  = ss * (1.0f / E_) - mu * mu;
    float rstd = rsqrtf(var + 1e-5f);
    float4 gv = ((const float4*)g)[tid];
    float4 bv = ((const float4*)bta)[tid];
    union { bf16_t h[4]; ushort4 u; } pk;
    pk.h[0] = (bf16_t)((v.x - mu) * rstd * gv.x + bv.x);
    pk.h[1] = (bf16_t)((v.y - mu) * rstd * gv.y + bv.y);
    pk.h[2] = (bf16_t)((v.z - mu) * rstd * gv.z + bv.z);
    pk.h[3] = (bf16_t)((v.w - mu) * rstd * gv.w + bv.w);
    ((ushort4*)(out + (size_t)row * E_))[tid] = pk.u;
}

// ---------------- split-K reduce (2 fp32 slices) + bias + resid + LN ---
__global__ __launch_bounds__(256) void ln_reduce2(
    const float* __restrict__ p, const float* __restrict__ bias,
    const float* __restrict__ resid, float* __restrict__ x1,
    const float* __restrict__ g, const float* __restrict__ bta,
    bf16_t* __restrict__ out)
{
    int row = blockIdx.x;
    int tid = threadIdx.x;
    size_t off = (size_t)row * E_;
    float4 v0 = ((const float4*)(p + off))[tid];
    float4 v1 = ((const float4*)(p + (size_t)NROW * E_ + off))[tid];
    float4 bb = ((const float4*)bias)[tid];
    float4 rr = ((const float4*)(resid + off))[tid];
    float4 v;
    v.x = v0.x + v1.x + bb.x + rr.x;
    v.y = v0.y + v1.y + bb.y + rr.y;
    v.z = v0.z + v1.z + bb.z + rr.z;
    v.w = v0.w + v1.w + bb.w + rr.w;
    ((float4*)(x1 + off))[tid] = v;
    float s  = v.x + v.y + v.z + v.w;
    float ss = v.x * v.x + v.y * v.y + v.z * v.z + v.w * v.w;
#pragma unroll
    for (int o = 32; o; o >>= 1) {
        s  += __shfl_xor(s, o);
        ss += __shfl_xor(ss, o);
    }
    __shared__ float red[8];
    int wave = tid >> 6, lane = tid & 63;
    if (lane == 0) { red[wave] = s; red[4 + wave] = ss; }
    __syncthreads();
    s  = red[0] + red[1] + red[2] + red[3];
    ss = red[4] + red[5] + red[6] + red[7];
    float mu   = s * (1.0f / E_);
    float var  = ss * (1.0f / E_) - mu * mu;
    float rstd = rsqrtf(var + 1e-5f);
    float4 gv = ((const float4*)g)[tid];
    float4 bv = ((const float4*)bta)[tid];
    union { bf16_t h[4]; ushort4 u; } pk;
    pk.h[0] = (bf16_t)((v.x - mu) * rstd * gv.x + bv.x);
    pk.h[1] = (bf16_t)((v.y - mu) * rstd * gv.y + bv.y);
    pk.h[2] = (bf16_t)((v.z - mu) * rstd * gv.z + bv.z);
    pk.h[3] = (bf16_t)((v.w - mu) * rstd * gv.w + bv.w);
    ((ushort4*)(out + off))[tid] = pk.u;
}

// ---------------- split-K reduce (2 fp32 slices) + bias + resid --------
__global__ __launch_bounds__(256) void add_reduce2(
    const float* __restrict__ p, const float* __restrict__ bias,
    const float* __restrict__ resid, float* __restrict__ out)
{
    int row = blockIdx.x;
    int tid = threadIdx.x;
    size_t off = (size_t)row * E_;
    float4 v0 = ((const float4*)(p + off))[tid];
    float4 v1 = ((const float4*)(p + (size_t)NROW * E_ + off))[tid];
    float4 bb = ((const float4*)bias)[tid];
    float4 rr = ((const float4*)(resid + off))[tid];
    float4 v;
    v.x = v0.x + v1.x + bb.x + rr.x;
    v.y = v0.y + v1.y + bb.y + rr.y;
    v.z = v0.z + v1.z + bb.z + rr.z;
    v.w = v0.w + v1.w + bb.w + rr.w;
    ((float4*)(out + off))[tid] = v;
}

// ------------------------- all weight transposes, one dispatch ----------
__global__ __launch_bounds__(256) void transpose_all(
    const float* __restrict__ Wq, const float* __restrict__ Wk,
    const float* __restrict__ Wv, const float* __restrict__ Wo,
    const float* __restrict__ W1, const float* __restrict__ W2,
    bf16_t* __restrict__ wqkv, bf16_t* __restrict__ wot,
    bf16_t* __restrict__ w1t, bf16_t* __restrict__ w2t)
{
    int l = blockIdx.x;
    const float* W; bf16_t* Wt; int K, N, bx, by;
    if (l < 4096) {
        int seg = l >> 10, r = l & 1023;
        K = E_; N = E_; bx = r & 31; by = r >> 5;
        if      (seg == 0) { W = Wq; Wt = wqkv; }
        else if (seg == 1) { W = Wk; Wt = wqkv + (size_t)E_ * E_; }
        else if (seg == 2) { W = Wv; Wt = wqkv + (size_t)2 * E_ * E_; }
        else               { W = Wo; Wt = wot; }
    } else if (l < 8192) {
        int r = l - 4096; K = E_; N = FF_; bx = r & 127; by = r >> 7;
        W = W1; Wt = w1t;
    } else {
        int r = l - 8192; K = FF_; N = E_; bx = r & 31; by = r >> 5;
        W = W2; Wt = w2t;
    }
    __shared__ float t[32][33];
    int n0 = bx * 32, k0 = by * 32;
    int tx = threadIdx.x & 31, ty = threadIdx.x >> 5;
#pragma unroll
    for (int i = 0; i < 4; ++i)
        t[ty + i * 8][tx] = W[(size_t)(k0 + ty + i * 8) * N + n0 + tx];
    __syncthreads();
#pragma unroll
    for (int i = 0; i < 4; ++i)
        Wt[(size_t)(n0 + ty + i * 8) * K + k0 + tx] = (bf16_t)t[tx][ty + i * 8];
}

// ----------------------------------------------------------- GEMM ------
// Distance-2 software pipeline, one lgkm-only barrier per K-step:
//   iter i: barrier; issue loads for i+2 (regs); MFMA on buf[i&1];
//           ds_write regs loaded at i-1 -> buf[(i+1)&1].
// The vmcnt wait before the ds_write is fine-grained (newer loads stay in
// flight) and the loads had a full iteration to land. Split-K via
// blockIdx.z (fp32 partials); V-transpose epilogue for QKV (n0 >= 2*E_).
#define BM 128
#define BN 128
#define BK 32

struct Pref { uint4 a0, a1, b0, b1; };

__device__ __forceinline__ Pref ld_tile(
    const bf16_t* Ag, const bf16_t* Bg, int k0, int lda, int ldb)
{
    Pref p;
    p.a0 = *(const uint4*)(Ag + k0);
    p.a1 = *(const uint4*)(Ag + k0 + (size_t)64 * lda);
    p.b0 = *(const uint4*)(Bg + k0);
    p.b1 = *(const uint4*)(Bg + k0 + (size_t)64 * ldb);
    return p;
}

__device__ __forceinline__ void st_tile(
    bf16_t* As, bf16_t* Bs, int sr, int sc, const Pref& p)
{
    *(uint4*)&As[sr * BK + sc]        = p.a0;
    *(uint4*)&As[(sr + 64) * BK + sc] = p.a1;
    *(uint4*)&Bs[sr * BK + sc]        = p.b0;
    *(uint4*)&Bs[(sr + 64) * BK + sc] = p.b1;
}

__device__ __forceinline__ void mfma_tile(
    const bf16_t* As, const bf16_t* Bs, f32x4 acc[4][4],
    int wm, int wn, int ml, int kq)
{
    bf16x8 af[4], bfr[4];
#pragma unroll
    for (int mi = 0; mi < 4; ++mi)
        af[mi] = *(const bf16x8*)&As[(wm + mi * 16 + ml) * BK + kq];
#pragma unroll
    for (int ni = 0; ni < 4; ++ni)
        bfr[ni] = *(const bf16x8*)&Bs[(wn + ni * 16 + ml) * BK + kq];
#pragma unroll
    for (int mi = 0; mi < 4; ++mi)
#pragma unroll
        for (int ni = 0; ni < 4; ++ni)
            acc[mi][ni] = __builtin_amdgcn_mfma_f32_16x16x32_bf16(
                af[mi], bfr[ni], acc[mi][ni], 0, 0, 0);
}

__global__ __launch_bounds__(256) void gemm_bt(
    const bf16_t* __restrict__ A, const bf16_t* __restrict__ Bt,
    const float* __restrict__ bias, const float* __restrict__ resid,
    void* __restrict__ Cout, bf16_t* __restrict__ vt_out,
    int M, int N, int K, int lda, int ldb,
    int has_bias, int do_relu, int has_resid, int out_bf16)
{
    __shared__ __attribute__((aligned(16))) bf16_t As[2][BM * BK];
    __shared__ __attribute__((aligned(16))) bf16_t Bs[2][BN * BK];
    int tid  = threadIdx.x;
    int lane = tid & 63, wave = tid >> 6;
    int m0 = blockIdx.x * BM, n0 = blockIdx.y * BN;
    int wm = (wave & 1) * 64, wn = (wave >> 1) * 64;
    int koff = blockIdx.z * K;
    f32x4 acc[4][4];
#pragma unroll
    for (int i = 0; i < 4; ++i)
#pragma unroll
        for (int j = 0; j < 4; ++j) acc[i][j] = (f32x4){0.f, 0.f, 0.f, 0.f};

    int sr = tid >> 2;            // 0..63 (rows sr, sr+64)
    int sc = (tid & 3) * 8;       // 0,8,16,24
    const int kq = (lane >> 4) * 8;
    const int ml = lane & 15;
    const bf16_t* Ag = A  + (size_t)(m0 + sr) * lda + koff + sc;
    const bf16_t* Bg = Bt + (size_t)(n0 + sr) * ldb + koff + sc;
    int niter = K / BK;           // always even in this launch set

    Pref pA, pB;
    // prologue: iter 0 staged directly into buf0; iter 1 loads -> pB
    st_tile(As[0], Bs[0], sr, sc, ld_tile(Ag, Bg, 0, lda, ldb));
    if (niter > 1) pB = ld_tile(Ag, Bg, BK, lda, ldb);

    for (int it = 0; it < niter; it += 2) {
        wg_barrier();                     // buf0 ready; buf1 readers done
        bool pfA = (it + 2 < niter);
        if (pfA) pA = ld_tile(Ag, Bg, (it + 2) * BK, lda, ldb);
        mfma_tile(As[0], Bs[0], acc, wm, wn, ml, kq);
        if (it + 1 < niter) st_tile(As[1], Bs[1], sr, sc, pB);
        if (it + 1 >= niter) break;

        wg_barrier();                     // buf1 ready; buf0 readers done
        bool pfB = (it + 3 < niter);
        if (pfB) pB = ld_tile(Ag, Bg, (it + 3) * BK, lda, ldb);
        mfma_tile(As[1], Bs[1], acc, wm, wn, ml, kq);
        if (pfA) st_tile(As[0], Bs[0], sr, sc, pA);
    }

    int r4 = (lane >> 4) * 4;
    if (gridDim.z > 1) {
        // split-K partial: fp32 [z][M][N]
        float* P = (float*)Cout + (size_t)blockIdx.z * M * N;
#pragma unroll
        for (int mi = 0; mi < 4; ++mi)
#pragma unroll
            for (int ni = 0; ni < 4; ++ni) {
                int col = n0 + wn + ni * 16 + ml;
#pragma unroll
                for (int r = 0; r < 4; ++r) {
                    int row = m0 + wm + mi * 16 + r4 + r;
                    P[(size_t)row * N + col] = acc[mi][ni][r];
                }
            }
        return;
    }
    if (vt_out && n0 >= 2 * E_) {
        // V slab of QKV: write transposed per-head Vt[bh][d][t]
#pragma unroll
        for (int mi = 0; mi < 4; ++mi)
#pragma unroll
            for (int ni = 0; ni < 4; ++ni) {
                int vcol = n0 + wn + ni * 16 + ml - 2 * E_;
                int h = vcol >> 6, d = vcol & 63;
                int row0 = m0 + wm + mi * 16 + r4;
                int b = row0 >> 11, t = row0 & (T_ - 1);
                union { bf16_t h4[4]; uint2 u; } pk;
#pragma unroll
                for (int r = 0; r < 4; ++r) pk.h4[r] = (bf16_t)acc[mi][ni][r];
                *(uint2*)&vt_out[((size_t)(b * H_ + h) * D_ + d) * T_ + t] = pk.u;
            }
        return;
    }
#pragma unroll
    for (int mi = 0; mi < 4; ++mi) {
#pragma unroll
        for (int ni = 0; ni < 4; ++ni) {
            int col = n0 + wn + ni * 16 + ml;
            float bval = has_bias ? bias[col] : 0.0f;
#pragma unroll
            for (int r = 0; r < 4; ++r) {
                int row = m0 + wm + mi * 16 + r4 + r;
                float v = acc[mi][ni][r] + bval;
                if (do_relu)   v = fmaxf(v, 0.0f);
                if (has_resid) v += resid[(size_t)row * N + col];
                if (out_bf16)
                    ((bf16_t*)Cout)[(size_t)row * N + col] = (bf16_t)v;
                else
                    ((float*)Cout)[(size_t)row * N + col] = v;
            }
        }
    }
}

// ------------------------------------------------- MFMA flash attention -
#define PSTR 72

struct TileState {
    f32x4 acc[4];
    float m1, l1;
};

__device__ __forceinline__ void tile_update(
    const bf16x8 kf[2][4], const bf16x8 vf[2][4], const bf16x8 qf[2],
    TileState& st, bf16_t* PsW, int ml, int r4, int kq8,
    bool diag, int ch, int qrow)
{
    f32x4 s[4];
#pragma unroll
    for (int nt = 0; nt < 4; ++nt) {
        s[nt] = (f32x4){0.f, 0.f, 0.f, 0.f};
#pragma unroll
        for (int ks = 0; ks < 2; ++ks)
            s[nt] = __builtin_amdgcn_mfma_f32_16x16x32_bf16(kf[ks][nt], qf[ks], s[nt], 0, 0, 0);
    }
    if (diag) {
#pragma unroll
        for (int nt = 0; nt < 4; ++nt)
#pragma unroll
            for (int r = 0; r < 4; ++r)
                if (ch * 64 + nt * 16 + r4 + r > qrow) s[nt][r] = -INFINITY;
    }
    float mx = -INFINITY;
#pragma unroll
    for (int nt = 0; nt < 4; ++nt)
#pragma unroll
        for (int r = 0; r < 4; ++r) mx = fmaxf(mx, s[nt][r]);
    mx = fmaxf(mx, __shfl_xor(mx, 16));
    mx = fmaxf(mx, __shfl_xor(mx, 32));
    float mn = fmaxf(st.m1, mx);
    float al = __expf(st.m1 - mn);
    st.m1 = mn;
    float sum = 0.f;
#pragma unroll
    for (int nt = 0; nt < 4; ++nt)
#pragma unroll
        for (int r = 0; r < 4; ++r) {
            float p = __expf(s[nt][r] - mn);
            s[nt][r] = p;
            sum += p;
        }
    sum += __shfl_xor(sum, 16);
    sum += __shfl_xor(sum, 32);
    st.l1 = st.l1 * al + sum;
#pragma unroll
    for (int dt = 0; dt < 4; ++dt)
#pragma unroll
        for (int r = 0; r < 4; ++r) st.acc[dt][r] *= al;

#pragma unroll
    for (int nt = 0; nt < 4; ++nt) {
        union { bf16_t h[4]; uint2 u; } pk;
#pragma unroll
        for (int r = 0; r < 4; ++r) pk.h[r] = (bf16_t)s[nt][r];
        *(uint2*)&PsW[ml * PSTR + nt * 16 + r4] = pk.u;
    }
#pragma unroll
    for (int ks = 0; ks < 2; ++ks) {
        bf16x8 pf = *(const bf16x8*)&PsW[ml * PSTR + ks * 32 + kq8];
#pragma unroll
        for (int dt = 0; dt < 4; ++dt)
            st.acc[dt] = __builtin_amdgcn_mfma_f32_16x16x32_bf16(vf[ks][dt], pf, st.acc[dt], 0, 0, 0);
    }
}

__global__ __launch_bounds__(256) void attn_mfma(
    const bf16_t* __restrict__ Qp, const bf16_t* __restrict__ Kp,
    const bf16_t* __restrict__ Vt, bf16_t* __restrict__ O)
{
    __shared__ __attribute__((aligned(16))) bf16_t Ks[2][64 * PSTR];
    __shared__ __attribute__((aligned(16))) bf16_t Vts[2][64 * PSTR];
    __shared__ __attribute__((aligned(16))) bf16_t Ps[4][16 * PSTR];

    int tid = threadIdx.x, lane = tid & 63, wave = tid >> 6;
    int ml  = lane & 15;
    int kq8 = (lane >> 4) * 8;
    int r4  = (lane >> 4) * 4;
    int bh = blockIdx.y, b = bh >> 4, h = bh & 15;
    size_t qk_base = (size_t)b * T_ * QS_ + h * D_;
    size_t vt_base = (size_t)bh * D_ * T_;
    size_t o_base  = (size_t)b * T_ * E_ + h * D_;

    int lo = blockIdx.x, hi = NTI - 1 - blockIdx.x;
    int qlo = lo * 64 + wave * 16;
    int qhi = hi * 64 + wave * 16;

    bf16x8 qfl[2], qfh[2];
#pragma unroll
    for (int ks = 0; ks < 2; ++ks) {
        bf16x8 a = *(const bf16x8*)&Qp[qk_base + (size_t)(qlo + ml) * QS_ + ks * 32 + kq8];
        bf16x8 c = *(const bf16x8*)&Qp[qk_base + (size_t)(qhi + ml) * QS_ + ks * 32 + kq8];
#pragma unroll
        for (int j = 0; j < 8; ++j) {
            a[j] = (bf16_t)((float)a[j] * 0.125f);
            c[j] = (bf16_t)((float)c[j] * 0.125f);
        }
        qfl[ks] = a; qfh[ks] = c;
    }

    TileState stl, sth;
#pragma unroll
    for (int dt = 0; dt < 4; ++dt) {
        stl.acc[dt] = (f32x4){0.f, 0.f, 0.f, 0.f};
        sth.acc[dt] = (f32x4){0.f, 0.f, 0.f, 0.f};
    }
    stl.m1 = -INFINITY; stl.l1 = 0.f;
    sth.m1 = -INFINITY; sth.l1 = 0.f;

    int r0 = tid >> 3, c0 = (tid & 7) * 8;
    int nch = hi + 1;

    {
        const bf16_t* kb = &Kp[qk_base + (size_t)r0 * QS_ + c0];
        const bf16_t* vb = &Vt[vt_base + (size_t)r0 * T_ + c0];
        uint4 k0v = *(const uint4*)kb;
        uint4 k1v = *(const uint4*)(kb + (size_t)32 * QS_);
        uint4 v0v = *(const uint4*)vb;
        uint4 v1v = *(const uint4*)(vb + (size_t)32 * T_);
        *(uint4*)&Ks[0][r0 * PSTR + c0]         = k0v;
        *(uint4*)&Ks[0][(r0 + 32) * PSTR + c0]  = k1v;
        *(uint4*)&Vts[0][r0 * PSTR + c0]        = v0v;
        *(uint4*)&Vts[0][(r0 + 32) * PSTR + c0] = v1v;
    }

    for (int ch = 0; ch < nch; ++ch) {
        int cur = ch & 1, nxt = cur ^ 1;
        __syncthreads();

        uint4 nk0, nk1, nv0, nv1;
        bool pf = (ch + 1 < nch);
        if (pf) {
            const bf16_t* kb = &Kp[qk_base + (size_t)((ch + 1) * 64 + r0) * QS_ + c0];
            const bf16_t* vb = &Vt[vt_base + (size_t)r0 * T_ + (ch + 1) * 64 + c0];
            nk0 = *(const uint4*)kb;
            nk1 = *(const uint4*)(kb + (size_t)32 * QS_);
            nv0 = *(const uint4*)vb;
            nv1 = *(const uint4*)(vb + (size_t)32 * T_);
        }

        bf16x8 kf[2][4], vf[2][4];
#pragma unroll
        for (int ks = 0; ks < 2; ++ks)
#pragma unroll
            for (int nt = 0; nt < 4; ++nt) {
                kf[ks][nt] = *(const bf16x8*)&Ks[cur][(nt * 16 + ml) * PSTR + ks * 32 + kq8];
                vf[ks][nt] = *(const bf16x8*)&Vts[cur][(nt * 16 + ml) * PSTR + ks * 32 + kq8];
            }

        tile_update(kf, vf, qfh, sth, Ps[wave], ml, r4, kq8,
                    ch == hi, ch, qhi + ml);
        if (ch <= lo)
            tile_update(kf, vf, qfl, stl, Ps[wave], ml, r4, kq8,
                        ch == lo, ch, qlo + ml);

        if (pf) {
            *(uint4*)&Ks[nxt][r0 * PSTR + c0]         = nk0;
            *(uint4*)&Ks[nxt][(r0 + 32) * PSTR + c0]  = nk1;
            *(uint4*)&Vts[nxt][r0 * PSTR + c0]        = nv0;
            *(uint4*)&Vts[nxt][(r0 + 32) * PSTR + c0] = nv1;
        }
    }

#pragma unroll
    for (int t = 0; t < 2; ++t) {
        TileState& st = t ? stl : sth;
        int qw = t ? qlo : qhi;
        float inv = 1.0f / st.l1;
#pragma unroll
        for (int dt = 0; dt < 4; ++dt) {
            union { bf16_t h[4]; uint2 u; } pk;
#pragma unroll
            for (int r = 0; r < 4; ++r) pk.h[r] = (bf16_t)(st.acc[dt][r] * inv);
            *(uint2*)&Ps[wave][ml * PSTR + dt * 16 + r4] = pk.u;
        }
        int row = lane >> 2, seg = (lane & 3) * 16;
        bf16x8 o0 = *(const bf16x8*)&Ps[wave][row * PSTR + seg];
        bf16x8 o1 = *(const bf16x8*)&Ps[wave][row * PSTR + seg + 8];
        size_t gp = o_base + (size_t)(qw + row) * E_ + seg;
        *(bf16x8*)&O[gp]     = o0;
        *(bf16x8*)&O[gp + 8] = o1;
    }
}

// ------------------------------------------------------------ launch ---
extern "C" void kernel_launch(void* const* d_in, const int* in_sizes, int n_in,
                              void* d_out, int out_size, void* d_ws, size_t ws_size,
                              hipStream_t stream)
{
    const float* x    = (const float*)d_in[0];
    const float* ln1g = (const float*)d_in[1];
    const float* ln1b = (const float*)d_in[2];
    const float* Wq   = (const float*)d_in[3];
    const float* Wk   = (const float*)d_in[4];
    const float* Wv   = (const float*)d_in[5];
    const float* Wo   = (const float*)d_in[6];
    const float* bo   = (const float*)d_in[7];
    const float* ln2g = (const float*)d_in[8];
    const float* ln2b = (const float*)d_in[9];
    const float* W1   = (const float*)d_in[10];
    const float* b1   = (const float*)d_in[11];
    const float* W2   = (const float*)d_in[12];
    const float* b2   = (const float*)d_in[13];

    char* ws = (char*)d_ws;
    const size_t MB = 1024ull * 1024ull;
    bf16_t* wqkv = (bf16_t*)(ws + 0 * MB);    // 3072x1024 bf16
    bf16_t* wot  = (bf16_t*)(ws + 6 * MB);    // 1024x1024 bf16
    bf16_t* w1t  = (bf16_t*)(ws + 8 * MB);    // 4096x1024 bf16
    bf16_t* w2t  = (bf16_t*)(ws + 16 * MB);   // 1024x4096 bf16
    bf16_t* xn   = (bf16_t*)(ws + 24 * MB);   // dead after QKV gemm
    bf16_t* QKV  = (bf16_t*)(ws + 32 * MB);   // Q,K slabs; dead after attn
    bf16_t* att  = (bf16_t*)(ws + 56 * MB);   // dead after Wo gemm
    float*  x1   = (float*)(ws + 64 * MB);    // live through add_reduce2
    bf16_t* hb   = (bf16_t*)(ws + 80 * MB);
    bf16_t* h1   = (bf16_t*)(ws + 88 * MB);   // 32 MB
    bf16_t* Vtb  = (bf16_t*)(ws + 88 * MB);   // 8 MB alias; dead before h1 write
    float*  part = (float*)(ws + 24 * MB);    // 2x16 MB fp32 split-K partials

    dim3 blk(256);

    transpose_all<<<dim3(12288), blk, 0, stream>>>(
        Wq, Wk, Wv, Wo, W1, W2, wqkv, wot, w1t, w2t);

    ln_kernel<<<dim3(NROW), blk, 0, stream>>>(x, ln1g, ln1b, xn);

    // fused QKV projection; V slab written transposed per-head into Vtb
    gemm_bt<<<dim3(NROW / BM, QS_ / BN), blk, 0, stream>>>(
        xn, wqkv, nullptr, nullptr, QKV, Vtb, NROW, QS_, E_, E_, E_, 0, 0, 0, 1);

    attn_mfma<<<dim3(NTI / 2, B_ * H_), blk, 0, stream>>>(
        QKV, QKV + E_, Vtb, att);

    // Wo projection: split-K x2 fp32 partials -> reduce + LN2 fused
    gemm_bt<<<dim3(NROW / BM, E_ / BN, 2), blk, 0, stream>>>(
        att, wot, nullptr, nullptr, part, nullptr, NROW, E_, E_ / 2, E_, E_, 0, 0, 0, 0);
    ln_reduce2<<<dim3(NROW), blk, 0, stream>>>(
        part, bo, x, x1, ln2g, ln2b, hb);

    // MLP up + bias + relu
    gemm_bt<<<dim3(NROW / BM, FF_ / BN), blk, 0, stream>>>(
        hb, w1t, b1, nullptr, h1, nullptr, NROW, FF_, E_, E_, E_, 1, 1, 0, 1);

    // MLP down: split-K x2 fp32 partials -> reduce + b2 + resid
    gemm_bt<<<dim3(NROW / BM, E_ / BN, 2), blk, 0, stream>>>(
        h1, w2t, nullptr, nullptr, part, nullptr, NROW, E_, FF_ / 2, FF_, FF_, 0, 0, 0, 0);
    add_reduce2<<<dim3(NROW), blk, 0, stream>>>(
        part, b2, x1, (float*)d_out);
}

// Round 9
// 346.775 us; speedup vs baseline: 1.3439x; 1.3439x over previous
//
#include <hip/hip_runtime.h>
#include <cmath>
#include <cstdint>
#include <cstddef>

typedef __bf16 bf16_t;
typedef __bf16 bf16x8 __attribute__((ext_vector_type(8)));
typedef float  f32x4  __attribute__((ext_vector_type(4)));

#define B_   2
#define T_   2048
#define E_   1024
#define H_   16
#define D_   64
#define FF_  4096
#define NROW (B_ * T_)   // 4096
#define QS_  (3 * E_)    // packed QKV row stride
#define NTI  (T_ / 64)   // 32 q-tiles

// ---------------------------------------------------------------- LN ----
__device__ __forceinline__ void ln_row(
    const float* __restrict__ x, const float* __restrict__ g,
    const float* __restrict__ bta, bf16_t* __restrict__ out, int row)
{
    int tid = threadIdx.x;
    const float4* xr = (const float4*)(x + (size_t)row * E_);
    float4 v = xr[tid];
    float s  = v.x + v.y + v.z + v.w;
    float ss = v.x * v.x + v.y * v.y + v.z * v.z + v.w * v.w;
#pragma unroll
    for (int off = 32; off; off >>= 1) {
        s  += __shfl_xor(s, off);
        ss += __shfl_xor(ss, off);
    }
    __shared__ float red[8];
    int wave = tid >> 6, lane = tid & 63;
    if (lane == 0) { red[wave] = s; red[4 + wave] = ss; }
    __syncthreads();
    s  = red[0] + red[1] + red[2] + red[3];
    ss = red[4] + red[5] + red[6] + red[7];
    float mu   = s * (1.0f / E_);
    float var  = ss * (1.0f / E_) - mu * mu;
    float rstd = rsqrtf(var + 1e-5f);
    float4 gv = ((const float4*)g)[tid];
    float4 bv = ((const float4*)bta)[tid];
    union { bf16_t h[4]; ushort4 u; } pk;
    pk.h[0] = (bf16_t)((v.x - mu) * rstd * gv.x + bv.x);
    pk.h[1] = (bf16_t)((v.y - mu) * rstd * gv.y + bv.y);
    pk.h[2] = (bf16_t)((v.z - mu) * rstd * gv.z + bv.z);
    pk.h[3] = (bf16_t)((v.w - mu) * rstd * gv.w + bv.w);
    ((ushort4*)(out + (size_t)row * E_))[tid] = pk.u;
}

// ---------------- split-K reduce (2 fp32 slices) + bias + resid + LN ---
__global__ __launch_bounds__(256) void ln_reduce2(
    const float* __restrict__ p, const float* __restrict__ bias,
    const float* __restrict__ resid, float* __restrict__ x1,
    const float* __restrict__ g, const float* __restrict__ bta,
    bf16_t* __restrict__ out)
{
    int row = blockIdx.x;
    int tid = threadIdx.x;
    size_t off = (size_t)row * E_;
    float4 v0 = ((const float4*)(p + off))[tid];
    float4 v1 = ((const float4*)(p + (size_t)NROW * E_ + off))[tid];
    float4 bb = ((const float4*)bias)[tid];
    float4 rr = ((const float4*)(resid + off))[tid];
    float4 v;
    v.x = v0.x + v1.x + bb.x + rr.x;
    v.y = v0.y + v1.y + bb.y + rr.y;
    v.z = v0.z + v1.z + bb.z + rr.z;
    v.w = v0.w + v1.w + bb.w + rr.w;
    ((float4*)(x1 + off))[tid] = v;
    float s  = v.x + v.y + v.z + v.w;
    float ss = v.x * v.x + v.y * v.y + v.z * v.z + v.w * v.w;
#pragma unroll
    for (int o = 32; o; o >>= 1) {
        s  += __shfl_xor(s, o);
        ss += __shfl_xor(ss, o);
    }
    __shared__ float red[8];
    int wave = tid >> 6, lane = tid & 63;
    if (lane == 0) { red[wave] = s; red[4 + wave] = ss; }
    __syncthreads();
    s  = red[0] + red[1] + red[2] + red[3];
    ss = red[4] + red[5] + red[6] + red[7];
    float mu   = s * (1.0f / E_);
    float var  = ss * (1.0f / E_) - mu * mu;
    float rstd = rsqrtf(var + 1e-5f);
    float4 gv = ((const float4*)g)[tid];
    float4 bv = ((const float4*)bta)[tid];
    union { bf16_t h[4]; ushort4 u; } pk;
    pk.h[0] = (bf16_t)((v.x - mu) * rstd * gv.x + bv.x);
    pk.h[1] = (bf16_t)((v.y - mu) * rstd * gv.y + bv.y);
    pk.h[2] = (bf16_t)((v.z - mu) * rstd * gv.z + bv.z);
    pk.h[3] = (bf16_t)((v.w - mu) * rstd * gv.w + bv.w);
    ((ushort4*)(out + off))[tid] = pk.u;
}

// ---------------- split-K reduce (2 fp32 slices) + bias + resid --------
__global__ __launch_bounds__(256) void add_reduce2(
    const float* __restrict__ p, const float* __restrict__ bias,
    const float* __restrict__ resid, float* __restrict__ out)
{
    int row = blockIdx.x;
    int tid = threadIdx.x;
    size_t off = (size_t)row * E_;
    float4 v0 = ((const float4*)(p + off))[tid];
    float4 v1 = ((const float4*)(p + (size_t)NROW * E_ + off))[tid];
    float4 bb = ((const float4*)bias)[tid];
    float4 rr = ((const float4*)(resid + off))[tid];
    float4 v;
    v.x = v0.x + v1.x + bb.x + rr.x;
    v.y = v0.y + v1.y + bb.y + rr.y;
    v.z = v0.z + v1.z + bb.z + rr.z;
    v.w = v0.w + v1.w + bb.w + rr.w;
    ((float4*)(out + off))[tid] = v;
}

// -------------- all weight transposes + LN1, one dispatch --------------
// blocks 0..12287: W[K][N] fp32 -> Wt[N][K] bf16 (32x32 tiles).
// blocks 12288..16383: LN1 row (l - 12288).
__global__ __launch_bounds__(256) void transpose_all(
    const float* __restrict__ Wq, const float* __restrict__ Wk,
    const float* __restrict__ Wv, const float* __restrict__ Wo,
    const float* __restrict__ W1, const float* __restrict__ W2,
    bf16_t* __restrict__ wqkv, bf16_t* __restrict__ wot,
    bf16_t* __restrict__ w1t, bf16_t* __restrict__ w2t,
    const float* __restrict__ x, const float* __restrict__ ln1g,
    const float* __restrict__ ln1b, bf16_t* __restrict__ xn)
{
    int l = blockIdx.x;
    if (l >= 12288) {
        ln_row(x, ln1g, ln1b, xn, l - 12288);
        return;
    }
    const float* W; bf16_t* Wt; int K, N, bx, by;
    if (l < 4096) {
        int seg = l >> 10, r = l & 1023;
        K = E_; N = E_; bx = r & 31; by = r >> 5;
        if      (seg == 0) { W = Wq; Wt = wqkv; }
        else if (seg == 1) { W = Wk; Wt = wqkv + (size_t)E_ * E_; }
        else if (seg == 2) { W = Wv; Wt = wqkv + (size_t)2 * E_ * E_; }
        else               { W = Wo; Wt = wot; }
    } else if (l < 8192) {
        int r = l - 4096; K = E_; N = FF_; bx = r & 127; by = r >> 7;
        W = W1; Wt = w1t;
    } else {
        int r = l - 8192; K = FF_; N = E_; bx = r & 31; by = r >> 5;
        W = W2; Wt = w2t;
    }
    __shared__ float t[32][33];
    int n0 = bx * 32, k0 = by * 32;
    int tx = threadIdx.x & 31, ty = threadIdx.x >> 5;
#pragma unroll
    for (int i = 0; i < 4; ++i)
        t[ty + i * 8][tx] = W[(size_t)(k0 + ty + i * 8) * N + n0 + tx];
    __syncthreads();
#pragma unroll
    for (int i = 0; i < 4; ++i)
        Wt[(size_t)(n0 + ty + i * 8) * K + k0 + tx] = (bf16_t)t[tx][ty + i * 8];
}

// ----------------------------------------------------------- GEMM ------
// r7-proven: single-barrier register-double-buffered K-loop (distance 1):
// prefetch next tile into VGPRs right after the barrier, MFMA on buf[cur],
// ds_write prefetch to buf[nxt]. VGPR 84, 2+ blocks/CU. Split-K via
// blockIdx.z (fp32 partials); V-transpose epilogue for QKV (n0 >= 2*E_).
#define BM 128
#define BN 128
#define BK 32

__global__ __launch_bounds__(256) void gemm_bt(
    const bf16_t* __restrict__ A, const bf16_t* __restrict__ Bt,
    const float* __restrict__ bias, const float* __restrict__ resid,
    void* __restrict__ Cout, bf16_t* __restrict__ vt_out,
    int M, int N, int K, int lda, int ldb,
    int has_bias, int do_relu, int has_resid, int out_bf16)
{
    __shared__ __attribute__((aligned(16))) bf16_t As[2][BM * BK];
    __shared__ __attribute__((aligned(16))) bf16_t Bs[2][BN * BK];
    int tid  = threadIdx.x;
    int lane = tid & 63, wave = tid >> 6;
    int m0 = blockIdx.x * BM, n0 = blockIdx.y * BN;
    int wm = (wave & 1) * 64, wn = (wave >> 1) * 64;
    int koff = blockIdx.z * K;
    f32x4 acc[4][4];
#pragma unroll
    for (int i = 0; i < 4; ++i)
#pragma unroll
        for (int j = 0; j < 4; ++j) acc[i][j] = (f32x4){0.f, 0.f, 0.f, 0.f};

    int sr = tid >> 2;            // 0..63 (rows sr, sr+64)
    int sc = (tid & 3) * 8;       // 0,8,16,24
    const int kq = (lane >> 4) * 8;
    const int ml = lane & 15;
    const bf16_t* Ag = A  + (size_t)(m0 + sr) * lda + koff + sc;
    const bf16_t* Bg = Bt + (size_t)(n0 + sr) * ldb + koff + sc;
    int niter = K / BK;

    // prologue: stage k-iter 0 into buffer 0
    {
        uint4 ra0 = *(const uint4*)Ag;
        uint4 ra1 = *(const uint4*)(Ag + (size_t)64 * lda);
        uint4 rb0 = *(const uint4*)Bg;
        uint4 rb1 = *(const uint4*)(Bg + (size_t)64 * ldb);
        *(uint4*)&As[0][sr * BK + sc]        = ra0;
        *(uint4*)&As[0][(sr + 64) * BK + sc] = ra1;
        *(uint4*)&Bs[0][sr * BK + sc]        = rb0;
        *(uint4*)&Bs[0][(sr + 64) * BK + sc] = rb1;
    }

    for (int it = 0; it < niter; ++it) {
        int cur = it & 1, nxt = cur ^ 1;
        __syncthreads();   // buf[cur] ready; prev iter's reads of buf[nxt] done

        // issue next tile's global loads (no wait — land during MFMA)
        uint4 ra0, ra1, rb0, rb1;
        bool pf = (it + 1 < niter);
        if (pf) {
            int k0 = (it + 1) * BK;
            ra0 = *(const uint4*)(Ag + k0);
            ra1 = *(const uint4*)(Ag + k0 + (size_t)64 * lda);
            rb0 = *(const uint4*)(Bg + k0);
            rb1 = *(const uint4*)(Bg + k0 + (size_t)64 * ldb);
        }

        bf16x8 af[4], bfr[4];
#pragma unroll
        for (int mi = 0; mi < 4; ++mi)
            af[mi] = *(const bf16x8*)&As[cur][(wm + mi * 16 + ml) * BK + kq];
#pragma unroll
        for (int ni = 0; ni < 4; ++ni)
            bfr[ni] = *(const bf16x8*)&Bs[cur][(wn + ni * 16 + ml) * BK + kq];
#pragma unroll
        for (int mi = 0; mi < 4; ++mi)
#pragma unroll
            for (int ni = 0; ni < 4; ++ni)
                acc[mi][ni] = __builtin_amdgcn_mfma_f32_16x16x32_bf16(
                    af[mi], bfr[ni], acc[mi][ni], 0, 0, 0);

        if (pf) {
            *(uint4*)&As[nxt][sr * BK + sc]        = ra0;
            *(uint4*)&As[nxt][(sr + 64) * BK + sc] = ra1;
            *(uint4*)&Bs[nxt][sr * BK + sc]        = rb0;
            *(uint4*)&Bs[nxt][(sr + 64) * BK + sc] = rb1;
        }
    }

    int r4 = (lane >> 4) * 4;
    if (gridDim.z > 1) {
        // split-K partial: fp32 [z][M][N]
        float* P = (float*)Cout + (size_t)blockIdx.z * M * N;
#pragma unroll
        for (int mi = 0; mi < 4; ++mi)
#pragma unroll
            for (int ni = 0; ni < 4; ++ni) {
                int col = n0 + wn + ni * 16 + ml;
#pragma unroll
                for (int r = 0; r < 4; ++r) {
                    int row = m0 + wm + mi * 16 + r4 + r;
                    P[(size_t)row * N + col] = acc[mi][ni][r];
                }
            }
        return;
    }
    if (vt_out && n0 >= 2 * E_) {
        // V slab of QKV: write transposed per-head Vt[bh][d][t]
#pragma unroll
        for (int mi = 0; mi < 4; ++mi)
#pragma unroll
            for (int ni = 0; ni < 4; ++ni) {
                int vcol = n0 + wn + ni * 16 + ml - 2 * E_;
                int h = vcol >> 6, d = vcol & 63;
                int row0 = m0 + wm + mi * 16 + r4;
                int b = row0 >> 11, t = row0 & (T_ - 1);
                union { bf16_t h4[4]; uint2 u; } pk;
#pragma unroll
                for (int r = 0; r < 4; ++r) pk.h4[r] = (bf16_t)acc[mi][ni][r];
                *(uint2*)&vt_out[((size_t)(b * H_ + h) * D_ + d) * T_ + t] = pk.u;
            }
        return;
    }
#pragma unroll
    for (int mi = 0; mi < 4; ++mi) {
#pragma unroll
        for (int ni = 0; ni < 4; ++ni) {
            int col = n0 + wn + ni * 16 + ml;
            float bval = has_bias ? bias[col] : 0.0f;
#pragma unroll
            for (int r = 0; r < 4; ++r) {
                int row = m0 + wm + mi * 16 + r4 + r;
                float v = acc[mi][ni][r] + bval;
                if (do_relu)   v = fmaxf(v, 0.0f);
                if (has_resid) v += resid[(size_t)row * N + col];
                if (out_bf16)
                    ((bf16_t*)Cout)[(size_t)row * N + col] = (bf16_t)v;
                else
                    ((float*)Cout)[(size_t)row * N + col] = v;
            }
        }
    }
}

// ------------------------------------------------- MFMA flash attention -
#define PSTR 72

struct TileState {
    f32x4 acc[4];
    float m1, l1;
};

__device__ __forceinline__ void tile_update(
    const bf16x8 kf[2][4], const bf16x8 vf[2][4], const bf16x8 qf[2],
    TileState& st, bf16_t* PsW, int ml, int r4, int kq8,
    bool diag, int ch, int qrow)
{
    f32x4 s[4];
#pragma unroll
    for (int nt = 0; nt < 4; ++nt) {
        s[nt] = (f32x4){0.f, 0.f, 0.f, 0.f};
#pragma unroll
        for (int ks = 0; ks < 2; ++ks)
            s[nt] = __builtin_amdgcn_mfma_f32_16x16x32_bf16(kf[ks][nt], qf[ks], s[nt], 0, 0, 0);
    }
    if (diag) {
#pragma unroll
        for (int nt = 0; nt < 4; ++nt)
#pragma unroll
            for (int r = 0; r < 4; ++r)
                if (ch * 64 + nt * 16 + r4 + r > qrow) s[nt][r] = -INFINITY;
    }
    float mx = -INFINITY;
#pragma unroll
    for (int nt = 0; nt < 4; ++nt)
#pragma unroll
        for (int r = 0; r < 4; ++r) mx = fmaxf(mx, s[nt][r]);
    mx = fmaxf(mx, __shfl_xor(mx, 16));
    mx = fmaxf(mx, __shfl_xor(mx, 32));
    float mn = fmaxf(st.m1, mx);
    float al = __expf(st.m1 - mn);
    st.m1 = mn;
    float sum = 0.f;
#pragma unroll
    for (int nt = 0; nt < 4; ++nt)
#pragma unroll
        for (int r = 0; r < 4; ++r) {
            float p = __expf(s[nt][r] - mn);
            s[nt][r] = p;
            sum += p;
        }
    sum += __shfl_xor(sum, 16);
    sum += __shfl_xor(sum, 32);
    st.l1 = st.l1 * al + sum;
#pragma unroll
    for (int dt = 0; dt < 4; ++dt)
#pragma unroll
        for (int r = 0; r < 4; ++r) st.acc[dt][r] *= al;

#pragma unroll
    for (int nt = 0; nt < 4; ++nt) {
        union { bf16_t h[4]; uint2 u; } pk;
#pragma unroll
        for (int r = 0; r < 4; ++r) pk.h[r] = (bf16_t)s[nt][r];
        *(uint2*)&PsW[ml * PSTR + nt * 16 + r4] = pk.u;
    }
#pragma unroll
    for (int ks = 0; ks < 2; ++ks) {
        bf16x8 pf = *(const bf16x8*)&PsW[ml * PSTR + ks * 32 + kq8];
#pragma unroll
        for (int dt = 0; dt < 4; ++dt)
            st.acc[dt] = __builtin_amdgcn_mfma_f32_16x16x32_bf16(vf[ks][dt], pf, st.acc[dt], 0, 0, 0);
    }
}

__global__ __launch_bounds__(256) void attn_mfma(
    const bf16_t* __restrict__ Qp, const bf16_t* __restrict__ Kp,
    const bf16_t* __restrict__ Vt, bf16_t* __restrict__ O)
{
    __shared__ __attribute__((aligned(16))) bf16_t Ks[2][64 * PSTR];
    __shared__ __attribute__((aligned(16))) bf16_t Vts[2][64 * PSTR];
    __shared__ __attribute__((aligned(16))) bf16_t Ps[4][16 * PSTR];

    int tid = threadIdx.x, lane = tid & 63, wave = tid >> 6;
    int ml  = lane & 15;
    int kq8 = (lane >> 4) * 8;
    int r4  = (lane >> 4) * 4;
    int bh = blockIdx.y, b = bh >> 4, h = bh & 15;
    size_t qk_base = (size_t)b * T_ * QS_ + h * D_;
    size_t vt_base = (size_t)bh * D_ * T_;
    size_t o_base  = (size_t)b * T_ * E_ + h * D_;

    int lo = blockIdx.x, hi = NTI - 1 - blockIdx.x;
    int qlo = lo * 64 + wave * 16;
    int qhi = hi * 64 + wave * 16;

    bf16x8 qfl[2], qfh[2];
#pragma unroll
    for (int ks = 0; ks < 2; ++ks) {
        bf16x8 a = *(const bf16x8*)&Qp[qk_base + (size_t)(qlo + ml) * QS_ + ks * 32 + kq8];
        bf16x8 c = *(const bf16x8*)&Qp[qk_base + (size_t)(qhi + ml) * QS_ + ks * 32 + kq8];
#pragma unroll
        for (int j = 0; j < 8; ++j) {
            a[j] = (bf16_t)((float)a[j] * 0.125f);
            c[j] = (bf16_t)((float)c[j] * 0.125f);
        }
        qfl[ks] = a; qfh[ks] = c;
    }

    TileState stl, sth;
#pragma unroll
    for (int dt = 0; dt < 4; ++dt) {
        stl.acc[dt] = (f32x4){0.f, 0.f, 0.f, 0.f};
        sth.acc[dt] = (f32x4){0.f, 0.f, 0.f, 0.f};
    }
    stl.m1 = -INFINITY; stl.l1 = 0.f;
    sth.m1 = -INFINITY; sth.l1 = 0.f;

    int r0 = tid >> 3, c0 = (tid & 7) * 8;
    int nch = hi + 1;

    {
        const bf16_t* kb = &Kp[qk_base + (size_t)r0 * QS_ + c0];
        const bf16_t* vb = &Vt[vt_base + (size_t)r0 * T_ + c0];
        uint4 k0v = *(const uint4*)kb;
        uint4 k1v = *(const uint4*)(kb + (size_t)32 * QS_);
        uint4 v0v = *(const uint4*)vb;
        uint4 v1v = *(const uint4*)(vb + (size_t)32 * T_);
        *(uint4*)&Ks[0][r0 * PSTR + c0]         = k0v;
        *(uint4*)&Ks[0][(r0 + 32) * PSTR + c0]  = k1v;
        *(uint4*)&Vts[0][r0 * PSTR + c0]        = v0v;
        *(uint4*)&Vts[0][(r0 + 32) * PSTR + c0] = v1v;
    }

    for (int ch = 0; ch < nch; ++ch) {
        int cur = ch & 1, nxt = cur ^ 1;
        __syncthreads();

        uint4 nk0, nk1, nv0, nv1;
        bool pf = (ch + 1 < nch);
        if (pf) {
            const bf16_t* kb = &Kp[qk_base + (size_t)((ch + 1) * 64 + r0) * QS_ + c0];
            const bf16_t* vb = &Vt[vt_base + (size_t)r0 * T_ + (ch + 1) * 64 + c0];
            nk0 = *(const uint4*)kb;
            nk1 = *(const uint4*)(kb + (size_t)32 * QS_);
            nv0 = *(const uint4*)vb;
            nv1 = *(const uint4*)(vb + (size_t)32 * T_);
        }

        bf16x8 kf[2][4], vf[2][4];
#pragma unroll
        for (int ks = 0; ks < 2; ++ks)
#pragma unroll
            for (int nt = 0; nt < 4; ++nt) {
                kf[ks][nt] = *(const bf16x8*)&Ks[cur][(nt * 16 + ml) * PSTR + ks * 32 + kq8];
                vf[ks][nt] = *(const bf16x8*)&Vts[cur][(nt * 16 + ml) * PSTR + ks * 32 + kq8];
            }

        tile_update(kf, vf, qfh, sth, Ps[wave], ml, r4, kq8,
                    ch == hi, ch, qhi + ml);
        if (ch <= lo)
            tile_update(kf, vf, qfl, stl, Ps[wave], ml, r4, kq8,
                        ch == lo, ch, qlo + ml);

        if (pf) {
            *(uint4*)&Ks[nxt][r0 * PSTR + c0]         = nk0;
            *(uint4*)&Ks[nxt][(r0 + 32) * PSTR + c0]  = nk1;
            *(uint4*)&Vts[nxt][r0 * PSTR + c0]        = nv0;
            *(uint4*)&Vts[nxt][(r0 + 32) * PSTR + c0] = nv1;
        }
    }

#pragma unroll
    for (int t = 0; t < 2; ++t) {
        TileState& st = t ? stl : sth;
        int qw = t ? qlo : qhi;
        float inv = 1.0f / st.l1;
#pragma unroll
        for (int dt = 0; dt < 4; ++dt) {
            union { bf16_t h[4]; uint2 u; } pk;
#pragma unroll
            for (int r = 0; r < 4; ++r) pk.h[r] = (bf16_t)(st.acc[dt][r] * inv);
            *(uint2*)&Ps[wave][ml * PSTR + dt * 16 + r4] = pk.u;
        }
        int row = lane >> 2, seg = (lane & 3) * 16;
        bf16x8 o0 = *(const bf16x8*)&Ps[wave][row * PSTR + seg];
        bf16x8 o1 = *(const bf16x8*)&Ps[wave][row * PSTR + seg + 8];
        size_t gp = o_base + (size_t)(qw + row) * E_ + seg;
        *(bf16x8*)&O[gp]     = o0;
        *(bf16x8*)&O[gp + 8] = o1;
    }
}

// ------------------------------------------------------------ launch ---
extern "C" void kernel_launch(void* const* d_in, const int* in_sizes, int n_in,
                              void* d_out, int out_size, void* d_ws, size_t ws_size,
                              hipStream_t stream)
{
    const float* x    = (const float*)d_in[0];
    const float* ln1g = (const float*)d_in[1];
    const float* ln1b = (const float*)d_in[2];
    const float* Wq   = (const float*)d_in[3];
    const float* Wk   = (const float*)d_in[4];
    const float* Wv   = (const float*)d_in[5];
    const float* Wo   = (const float*)d_in[6];
    const float* bo   = (const float*)d_in[7];
    const float* ln2g = (const float*)d_in[8];
    const float* ln2b = (const float*)d_in[9];
    const float* W1   = (const float*)d_in[10];
    const float* b1   = (const float*)d_in[11];
    const float* W2   = (const float*)d_in[12];
    const float* b2   = (const float*)d_in[13];

    char* ws = (char*)d_ws;
    const size_t MB = 1024ull * 1024ull;
    bf16_t* wqkv = (bf16_t*)(ws + 0 * MB);    // 3072x1024 bf16
    bf16_t* wot  = (bf16_t*)(ws + 6 * MB);    // 1024x1024 bf16
    bf16_t* w1t  = (bf16_t*)(ws + 8 * MB);    // 4096x1024 bf16
    bf16_t* w2t  = (bf16_t*)(ws + 16 * MB);   // 1024x4096 bf16
    bf16_t* xn   = (bf16_t*)(ws + 24 * MB);   // dead after QKV gemm
    bf16_t* QKV  = (bf16_t*)(ws + 32 * MB);   // Q,K slabs; dead after attn
    bf16_t* att  = (bf16_t*)(ws + 56 * MB);   // dead after Wo gemm
    float*  x1   = (float*)(ws + 64 * MB);    // live through add_reduce2
    bf16_t* hb   = (bf16_t*)(ws + 80 * MB);
    bf16_t* h1   = (bf16_t*)(ws + 88 * MB);   // 32 MB
    bf16_t* Vtb  = (bf16_t*)(ws + 88 * MB);   // 8 MB alias; dead before h1 write
    float*  part = (float*)(ws + 24 * MB);    // 2x16 MB fp32 split-K partials

    dim3 blk(256);

    // weight transposes + LN1 in one dispatch
    transpose_all<<<dim3(16384), blk, 0, stream>>>(
        Wq, Wk, Wv, Wo, W1, W2, wqkv, wot, w1t, w2t, x, ln1g, ln1b, xn);

    // fused QKV projection; V slab written transposed per-head into Vtb
    gemm_bt<<<dim3(NROW / BM, QS_ / BN), blk, 0, stream>>>(
        xn, wqkv, nullptr, nullptr, QKV, Vtb, NROW, QS_, E_, E_, E_, 0, 0, 0, 1);

    attn_mfma<<<dim3(NTI / 2, B_ * H_), blk, 0, stream>>>(
        QKV, QKV + E_, Vtb, att);

    // Wo projection: split-K x2 fp32 partials -> reduce + LN2 fused
    gemm_bt<<<dim3(NROW / BM, E_ / BN, 2), blk, 0, stream>>>(
        att, wot, nullptr, nullptr, part, nullptr, NROW, E_, E_ / 2, E_, E_, 0, 0, 0, 0);
    ln_reduce2<<<dim3(NROW), blk, 0, stream>>>(
        part, bo, x, x1, ln2g, ln2b, hb);

    // MLP up + bias + relu
    gemm_bt<<<dim3(NROW / BM, FF_ / BN), blk, 0, stream>>>(
        hb, w1t, b1, nullptr, h1, nullptr, NROW, FF_, E_, E_, E_, 1, 1, 0, 1);

    // MLP down: split-K x2 fp32 partials -> reduce + b2 + resid
    gemm_bt<<<dim3(NROW / BM, E_ / BN, 2), blk, 0, stream>>>(
        h1, w2t, nullptr, nullptr, part, nullptr, NROW, E_, FF_ / 2, FF_, FF_, 0, 0, 0, 0);
    add_reduce2<<<dim3(NROW), blk, 0, stream>>>(
        part, b2, x1, (float*)d_out);
}